// Round 6
// baseline (294.575 us; speedup 1.0000x reference)
//
#include <hip/hip_runtime.h>

// Masked 3x3 conv as implicit GEMM over GATHERED pixels (mask==1 only).
//   C[f][p] = sum_{tap,c} Wt[f][tap*512+c] * Xt[(h_p+dh)*194+(w_p+dw)][c]
//   out = conv*mask + b  ==  bias at unmasked px, conv+bias at masked px.
// Round 10: DENSE EPILOGUE. conv wrote 87MB for 37.7MB logical (scattered
// 4B stores -> partial-line RFO, +40MB fetch), while mega_prep separately
// bias-filled the same 75.5MB buffer. Now conv's epilogue writes its owned
// pixel span DENSELY (sorted list -> spans partition [0,HW)): stage acc in
// LDS, build span-local px->slot map from the block's 128 list entries,
// stream full-line stores of (slot>=0 ? acc+bias : bias). bias_fill deleted
// from mega_prep. R8's failure mode (fill evicted before scatter) is gone:
// fill and scatter are the same store.

typedef unsigned short ushort_t;
typedef __attribute__((ext_vector_type(8))) __bf16 bf16x8;
typedef __attribute__((ext_vector_type(4))) float f32x4;
typedef __attribute__((ext_vector_type(8))) unsigned short ushort8;

#define IMG_W 192
#define IMG_H 192
#define HW    36864       // 192*192
#define PAD_W 194
#define C_IN  512
#define F_OUT 512
#define KTOT  4608        // 9*512
#define NCBLK 144         // compact blocks (256 px each)
#define EPI_CHUNK 1024    // dense-epilogue span chunk (px)

__device__ __forceinline__ unsigned short f2bf(float f) {
  unsigned int u = __builtin_bit_cast(unsigned int, f);
  u += 0x7fffu + ((u >> 16) & 1u);
  return (unsigned short)(u >> 16);
}

__device__ __forceinline__ void async16(const void* g, void* l) {
  // 16B/lane global->LDS DMA; LDS dest is wave-uniform base + lane*16
  __builtin_amdgcn_global_load_lds(
      (const __attribute__((address_space(1))) unsigned int*)g,
      (__attribute__((address_space(3))) unsigned int*)l, 16, 0, 0);
}

// ============ mega_prep: ALL non-GEMM work in one dispatch ============
// blocks [0,4608):     prep_x  (x NCHW fp32 -> padded NHWC bf16 interior)
// blocks [4608,4801):  halo_zero (772 border pixels of Xt, 16B/thread)
// blocks [4801,5825):  prep_w  (w [f][c][3][3] -> Wt [f][tap*512+c])
// blocks [5825,5969):  compact_scatter (self-computed prefix from mask)
// (bias broadcast REMOVED -- now done by conv_gemm's dense epilogue)
__global__ void mega_prep(const float* __restrict__ x, const float* __restrict__ w,
                          const int* __restrict__ mask,
                          ushort_t* __restrict__ Xt, ushort_t* __restrict__ Wt,
                          int* __restrict__ list, int* __restrict__ counter) {
  __shared__ float tile[64][65];
  __shared__ int red[4], wpc[4], woff[4];
  const int bid = blockIdx.x;
  const int tid = threadIdx.x;

  if (bid < 4608) {
    // ---- prep_x ---- (byte-identical; 64c x 64w LDS transpose)
    const int p  = bid;
    const int w0 = (p % 3) * 64;
    const int c0 = ((p / 3) & 7) * 64;
    const int h  = p / 24;

    const int wl_r = tid & 63;
    const int cg_r = tid >> 6;
    const float* src = x + (size_t)(c0 + cg_r * 16) * HW + (size_t)h * IMG_W + w0 + wl_r;
#pragma unroll
    for (int cc = 0; cc < 16; ++cc)
      tile[cg_r * 16 + cc][wl_r] = src[(size_t)cc * HW];
    __syncthreads();

    const int wl = tid >> 2;
    const int cg = tid & 3;
    ushort_t* dst = Xt + ((size_t)(h + 1) * PAD_W + (w0 + wl + 1)) * C_IN + c0 + cg * 16;
    ushort8 v0, v1;
#pragma unroll
    for (int cc = 0; cc < 8; ++cc) v0[cc] = f2bf(tile[cg * 16 + cc][wl]);
#pragma unroll
    for (int cc = 0; cc < 8; ++cc) v1[cc] = f2bf(tile[cg * 16 + 8 + cc][wl]);
    *(ushort8*)dst = v0;
    *(ushort8*)(dst + 8) = v1;
  } else if (bid < 4801) {
    // ---- halo_zero ---- 772 border pixels x 1KB, 16B per thread
    const int idx = (bid - 4608) * 256 + tid;   // 49408 = 772*64 stores
    const int p   = idx >> 6;                   // halo pixel 0..771
    const int off = (idx & 63) * 8;             // ushort offset (16B chunks)
    int r, c;
    if (p < 388) { r = (p >= 194) ? 193 : 0; c = (p >= 194) ? p - 194 : p; }
    else         { int q = p - 388; r = 1 + (q >> 1); c = (q & 1) ? 193 : 0; }
    ushort8 z = {0, 0, 0, 0, 0, 0, 0, 0};
    *(ushort8*)(Xt + ((size_t)r * PAD_W + c) * C_IN + off) = z;
  } else if (bid < 5825) {
    // ---- prep_w ----
    const int idx = (bid - 4801) * 256 + tid;   // f*512 + c
    const int f = idx >> 9;
    const int c = idx & 511;
    const float* src = w + (size_t)idx * 9;
    float v[9];
#pragma unroll
    for (int t = 0; t < 9; ++t) v[t] = src[t];
    ushort_t* dst = Wt + (size_t)f * KTOT + c;
#pragma unroll
    for (int t = 0; t < 9; ++t) dst[t * C_IN] = f2bf(v[t]);
  } else {
    // ---- compact_scatter, self-computed prefix (no atomics, no 2nd phase).
    // list comes out globally SORTED ascending. mask is 144KB -> L2-hot.
    const int cbid = bid - 5825;
    const int lane = tid & 63;
    const int wave = tid >> 6;
    const int i = cbid * 256 + tid;
    const int m = mask[i];
    unsigned long long b = __ballot(m != 0);
    // per-thread count of masked pixels in [0, cbid*256)
    int pcnt = 0;
    for (int k = tid; k < cbid * 256; k += 256) pcnt += (mask[k] != 0) ? 1 : 0;
#pragma unroll
    for (int off = 32; off; off >>= 1) pcnt += __shfl_down(pcnt, off);
    if (lane == 0) { red[wave] = pcnt; wpc[wave] = __popcll(b); }
    __syncthreads();
    if (tid == 0) {
      const int acc = red[0] + red[1] + red[2] + red[3];   // exclusive prefix
      woff[0] = acc;
      woff[1] = acc + wpc[0];
      woff[2] = acc + wpc[0] + wpc[1];
      woff[3] = acc + wpc[0] + wpc[1] + wpc[2];
      if (cbid == NCBLK - 1)
        counter[0] = acc + wpc[0] + wpc[1] + wpc[2] + wpc[3];  // total
    }
    __syncthreads();
    if (m) list[woff[wave] + __popcll(b & ((1ull << lane) - 1ull))] = i;
  }
}

// ---------------- implicit GEMM over gathered pixels, BK=64 ----------------
// K-loop byte-identical to the R7 control; epilogue replaced by dense
// span writer (this block's span = [list[n0-1]+1, list[n0+127]+1), sorted
// list => spans partition [0,HW); 4 y-blocks write disjoint rows).
__global__ __launch_bounds__(256, 3) void conv_gemm(
    const ushort_t* __restrict__ Wt, const ushort_t* __restrict__ Xt,
    const float* __restrict__ bias, const int* __restrict__ list,
    const int* __restrict__ counter, float* __restrict__ out) {
  __shared__ __align__(16) ushort_t As[128 * 64];  // [m 0..127][k 0..63], swizzled
  __shared__ __align__(16) ushort_t Bs[128 * 64];  // [p 0..127][k 0..63], swizzled
  // epilogue aliases: sm = 32x132 f32 (16.9KB, As + start of Bs);
  // slot = 1024 ints at Bs+1024B (17.4..21.5KB) -- no overlap with sm.
  float* sm  = (float*)As;
  int* slot  = (int*)((char*)Bs + 1024);

  const int count = counter[0];
  const int n0 = blockIdx.x * 128;
  const int m0 = blockIdx.y * 128;
  const int tid  = threadIdx.x;

  // ---- pixel-span ownership (list sorted): spans partition [0, HW) ----
  int lo_pix, hi_pix;
  {
    const int loPos = n0, hiPos = n0 + 128;
    lo_pix = (loPos == 0) ? 0 : ((loPos <= count) ? list[loPos - 1] + 1 : HW);
    hi_pix = (hiPos <= count) ? list[hiPos - 1] + 1 : HW;
    if (hi_pix < lo_pix) hi_pix = lo_pix;
  }

  if (n0 >= count) {
    // inactive block: dense bias fill of owned span (only the first block
    // past count owns a nonempty tail span; count==0 -> block x=0 fills all)
    for (int rr = 0; rr < 128; ++rr) {
      const float bv = bias[m0 + rr];
      float* o = out + (size_t)(m0 + rr) * HW;
      for (int p = lo_pix + tid; p < hi_pix; p += 256) o[p] = bv;
    }
    return;
  }

  const int lane = tid & 63;
  const int wave = tid >> 6;
  const int wm   = wave >> 1;
  const int wn   = wave & 1;

  // this thread's list entry (for the epilogue slot map)
  const int mypix = (tid < 128 && n0 + tid < count) ? list[n0 + tid] : -1;

  // ---- staging role: wave w stages rows [w*32, w*32+32) of A and B, via
  // 4 issues of 1KB (8 rows each). lane -> (row_rel = lane>>3, phys = lane&7).
  // Swizzle: phys slot p at row r holds logical chunk p ^ (r&7); here
  // r&7 == lane>>3, so each lane's logical chunk q is loop-invariant.
  const int rrel = lane >> 3;
  const int q    = (lane & 7) ^ rrel;

  const ushort_t* aSrc = Wt + (size_t)(m0 + wave * 32 + rrel) * KTOT + q * 8;

  unsigned int bOffs[4];
#pragma unroll
  for (int ii = 0; ii < 4; ++ii) {
    const int pos = n0 + wave * 32 + ii * 8 + rrel;
    const int pix = (pos < count) ? list[pos] : 0;
    const int hh = pix / IMG_W, ww = pix - hh * IMG_W;
    bOffs[ii] = ((hh + 1) * PAD_W + (ww + 1)) * C_IN + q * 8;
  }

  ushort_t* aDst = &As[wave * 32 * 64];  // + ii*512 per issue (8 rows x 64)
  ushort_t* bDst = &Bs[wave * 32 * 64];

  const int col  = lane & 15;
  const int quad = lane >> 4;

  f32x4 acc[4][4] = {};

  // initial staging (kk=0: tap 0, kc 0)
  {
    const int toff0 = -(PAD_W + 1) * C_IN;
#pragma unroll
    for (int ii = 0; ii < 4; ++ii) {
      async16(aSrc + (size_t)ii * 8 * KTOT, aDst + ii * 512);
      async16(Xt + (int)bOffs[ii] + toff0, bDst + ii * 512);
    }
  }

#pragma unroll 1
  for (int kk = 0; kk < 72; ++kk) {
    __syncthreads();   // staging for kk ready (drains vmcnt; DMA was in
                       // flight during the previous chunk's MFMA burst)
    bf16x8 af[2][4], bfr[2][4];
#pragma unroll
    for (int s = 0; s < 2; ++s) {
#pragma unroll
      for (int i = 0; i < 4; ++i) {
        const int row = wm * 64 + i * 16 + col;
        af[s][i] = *(const bf16x8*)&As[row * 64 + ((s * 4 + quad) ^ (row & 7)) * 8];
      }
#pragma unroll
      for (int j = 0; j < 4; ++j) {
        const int row = wn * 64 + j * 16 + col;
        bfr[s][j] = *(const bf16x8*)&Bs[row * 64 + ((s * 4 + quad) ^ (row & 7)) * 8];
      }
    }
    if (kk < 71) {
      __syncthreads();   // all waves done reading LDS; safe to overwrite
      const int kn   = kk + 1;
      const int tapn = kn >> 3;
      const int kcn  = (kn & 7) * 64;
      const int toffn = ((tapn / 3) * PAD_W + (tapn % 3) - (PAD_W + 1)) * C_IN;
      const int aoffn = tapn * 512 + kcn;
#pragma unroll
      for (int ii = 0; ii < 4; ++ii) {
        async16(aSrc + (size_t)ii * 8 * KTOT + aoffn, aDst + ii * 512);
        async16(Xt + (int)bOffs[ii] + toffn + kcn, bDst + ii * 512);
      }
    }
#pragma unroll
    for (int s = 0; s < 2; ++s)
#pragma unroll
      for (int i = 0; i < 4; ++i)
#pragma unroll
        for (int j = 0; j < 4; ++j)
          acc[i][j] = __builtin_amdgcn_mfma_f32_16x16x32_bf16(af[s][i], bfr[s][j],
                                                              acc[i][j], 0, 0, 0);
  }

  // ---- dense epilogue: write owned span [lo_pix,hi_pix) for all 128 rows.
  // Per i (fully unrolled -- keeps acc indices static, rule #20): stage
  // 32 rows x 128 px of acc into sm, then stream the span densely with
  // slot-mapped values. C/D frag mapping: col=lane&15, row=quad*4+r.
  __syncthreads();   // all MFMA-phase LDS reads complete before aliasing
#pragma unroll
  for (int i = 0; i < 4; ++i) {
    // rows covered this iter: rI = wm*16+quad*4+r  ->  mrow = m0+(rI>>4)*64+i*16+(rI&15)
#pragma unroll
    for (int j = 0; j < 4; ++j)
#pragma unroll
      for (int r = 0; r < 4; ++r)
        sm[(wm * 16 + quad * 4 + r) * 132 + wn * 64 + j * 16 + col] = acc[i][j][r];
    __syncthreads();
#pragma unroll 1
    for (int c0 = lo_pix; c0 < hi_pix; c0 += EPI_CHUNK) {
      const int c1 = (c0 + EPI_CHUNK < hi_pix) ? c0 + EPI_CHUNK : hi_pix;
#pragma unroll
      for (int t = 0; t < EPI_CHUNK / 256; ++t) slot[t * 256 + tid] = -1;
      __syncthreads();
      if (mypix >= c0 && mypix < c1) slot[mypix - c0] = tid;
      __syncthreads();
#pragma unroll 1
      for (int rI = 0; rI < 32; ++rI) {
        const int mrow = m0 + (rI >> 4) * 64 + i * 16 + (rI & 15);
        const float bv = bias[mrow];
        const float* smr = sm + rI * 132;
        float* o = out + (size_t)mrow * HW;
        for (int p = c0 + tid; p < c1; p += 256) {
          const int s = slot[p - c0];
          o[p] = (s >= 0) ? smr[s] + bv : bv;
        }
      }
      __syncthreads();   // slot safe to rebuild next chunk
    }
    __syncthreads();     // sm safe to restage next i
  }
}

extern "C" void kernel_launch(void* const* d_in, const int* in_sizes, int n_in,
                              void* d_out, int out_size, void* d_ws, size_t ws_size,
                              hipStream_t stream) {
  const float* x    = (const float*)d_in[0];  // [512][192][192]
  const float* w    = (const float*)d_in[1];  // [512][512][3][3]
  const float* bias = (const float*)d_in[2];  // [512]
  const int*   mask = (const int*)d_in[3];    // [192][192]
  float* out = (float*)d_out;                 // [512][192][192]

  // ws layout: list (36864 int) | counter | pad | Xt (38.5MB) | Wt (4.7MB)
  int* list    = (int*)d_ws;
  int* counter = list + HW;
  ushort_t* Xt = (ushort_t*)((char*)d_ws + 148096);   // 128B-aligned
  ushort_t* Wt = Xt + (size_t)PAD_W * PAD_W * C_IN;

  mega_prep<<<dim3(5969), 256, 0, stream>>>(x, w, mask, Xt, Wt, list, counter);
  conv_gemm<<<dim3((HW + 127) / 128, F_OUT / 128), 256, 0, stream>>>(
      Wt, Xt, bias, list, counter, out);
}